// Round 1
// baseline (18579.013 us; speedup 1.0000x reference)
//
#include <hip/hip_runtime.h>
#include <hip/hip_bf16.h>
#include <cstdint>
#include <cstddef>

// GRU: T=256, B=128, I=H=1024, 3H=3072. fp32 in/out.
// Phase 1: xg[t,b,g] = sum_i x[t,b,i]*w_ih[g,i] + b_ih[g]   (bf16 MFMA GEMM)
// Phase 2: persistent 256-block scan; W_hh slice in VGPRs; hi/lo bf16 h split.

typedef __attribute__((ext_vector_type(4))) float f32x4;
typedef __attribute__((ext_vector_type(8))) short s16x8;
typedef __attribute__((ext_vector_type(4))) unsigned short u16x4;

static __device__ __forceinline__ unsigned short f2bf(float f) {
  union { float f; unsigned u; } v; v.f = f;
  unsigned u = v.u;
  u += 0x7FFFu + ((u >> 16) & 1u);   // round-to-nearest-even
  return (unsigned short)(u >> 16);
}
static __device__ __forceinline__ float bf2f(unsigned short h) {
  union { unsigned u; float f; } v; v.u = ((unsigned)h) << 16;
  return v.f;
}

// ---------------- Phase 1: xg GEMM ----------------
// 128x128 tile, BK=64, 4 waves, fp32->bf16 reg-staged LDS (+8 pad kills conflicts)
template<bool XG_F32>
__global__ __launch_bounds__(256)
void xg_gemm(const float* __restrict__ X,     // [32768,1024]
             const float* __restrict__ W,     // [3072,1024]  (B^T layout)
             const float* __restrict__ bias,  // [3072]
             void* __restrict__ xg)           // [32768,3072] f32 or bf16
{
  __shared__ unsigned short Al[128][72];
  __shared__ unsigned short Bl[128][72];
  const int tid = threadIdx.x;
  const int lane = tid & 63;
  const int wv = tid >> 6;
  const int wm = (wv & 1) * 64;
  const int wn = (wv >> 1) * 64;
  const int m0 = blockIdx.y * 128;
  const int n0 = blockIdx.x * 128;
  const int r16 = lane & 15, r4 = lane >> 4;
  f32x4 acc[4][4] = {};

  for (int k0 = 0; k0 < 1024; k0 += 64) {
    __syncthreads();
    #pragma unroll
    for (int i = 0; i < 8; ++i) {
      int f4 = i * 256 + tid;           // 0..2047 float4 slots of the 128x64 tile
      int row = f4 >> 4;
      int c4 = f4 & 15;
      f32x4 a = *(const f32x4*)(X + (size_t)(m0 + row) * 1024 + k0 + c4 * 4);
      f32x4 b = *(const f32x4*)(W + (size_t)(n0 + row) * 1024 + k0 + c4 * 4);
      u16x4 ua = { f2bf(a.x), f2bf(a.y), f2bf(a.z), f2bf(a.w) };
      u16x4 ub = { f2bf(b.x), f2bf(b.y), f2bf(b.z), f2bf(b.w) };
      *(u16x4*)&Al[row][c4 * 4] = ua;
      *(u16x4*)&Bl[row][c4 * 4] = ub;
    }
    __syncthreads();
    #pragma unroll
    for (int kk = 0; kk < 64; kk += 32) {
      s16x8 af[4], bf[4];
      #pragma unroll
      for (int mi = 0; mi < 4; ++mi)
        af[mi] = *(const s16x8*)&Al[wm + mi * 16 + r16][kk + r4 * 8];
      #pragma unroll
      for (int ni = 0; ni < 4; ++ni)
        bf[ni] = *(const s16x8*)&Bl[wn + ni * 16 + r16][kk + r4 * 8];
      #pragma unroll
      for (int mi = 0; mi < 4; ++mi)
        #pragma unroll
        for (int ni = 0; ni < 4; ++ni)
          acc[mi][ni] = __builtin_amdgcn_mfma_f32_16x16x32_bf16(af[mi], bf[ni], acc[mi][ni], 0, 0, 0);
    }
  }
  #pragma unroll
  for (int ni = 0; ni < 4; ++ni) {
    float bv = bias[n0 + wn + ni * 16 + r16];
    #pragma unroll
    for (int mi = 0; mi < 4; ++mi) {
      #pragma unroll
      for (int r = 0; r < 4; ++r) {
        int m = m0 + wm + mi * 16 + r4 * 4 + r;
        int n = n0 + wn + ni * 16 + r16;
        float v = acc[mi][ni][r] + bv;
        if (XG_F32) ((float*)xg)[(size_t)m * 3072 + n] = v;
        else        ((unsigned short*)xg)[(size_t)m * 3072 + n] = f2bf(v);
      }
    }
  }
}

// ---------------- Phase 2: persistent GRU scan ----------------
// grid (64,4): cg=column-group (16 h-cols -> 48 gate rows), bg=batch-group (32 rows).
// 512 thr = 8 waves; wave wv owns K-eighth [wv*128, wv*128+128).
// W_hh fragments live in VGPRs (bw[3][4]). h broadcast = global bf16 hi/lo ping-pong.
template<bool XG_F32>
__global__ __launch_bounds__(512)
void gru_scan(const void* __restrict__ xg_,
              const float* __restrict__ Whh,   // [3072,1024]
              const float* __restrict__ bhh,   // [3072]
              float* __restrict__ out,         // [256,128,1024]
              unsigned short* __restrict__ hbc,// 2 parities x (hi,lo) x [128][1024]
              unsigned int* __restrict__ bar)  // 4 counters, 128B apart
{
  __shared__ float part[8][3][2][16][20];   // [ks][gate][mtile][row][col+pad]
  const int tid = threadIdx.x;
  const int lane = tid & 63;
  const int wv = tid >> 6;        // K-eighth
  const int cg = blockIdx.x;      // 0..63
  const int bg = blockIdx.y;      // 0..3
  const int c0 = cg * 16;
  const int b0 = bg * 32;
  const int r16 = lane & 15, r4 = lane >> 4;

  // Load this wave's W_hh fragments into registers (once).
  s16x8 bw[3][4];
  #pragma unroll
  for (int n = 0; n < 3; ++n) {
    const float* wrow = Whh + (size_t)(n * 1024 + c0 + r16) * 1024;
    #pragma unroll
    for (int kc = 0; kc < 4; ++kc) {
      int k = wv * 128 + kc * 32 + r4 * 8;
      f32x4 v0 = *(const f32x4*)(wrow + k);
      f32x4 v1 = *(const f32x4*)(wrow + k + 4);
      s16x8 f;
      f[0] = (short)f2bf(v0.x); f[1] = (short)f2bf(v0.y);
      f[2] = (short)f2bf(v0.z); f[3] = (short)f2bf(v0.w);
      f[4] = (short)f2bf(v1.x); f[5] = (short)f2bf(v1.y);
      f[6] = (short)f2bf(v1.z); f[7] = (short)f2bf(v1.w);
      bw[n][kc] = f;
    }
  }

  const int p_b = tid >> 4;       // 0..31 (batch within group)
  const int p_c = tid & 15;       // h-col within group
  const float bR = bhh[c0 + p_c];
  const float bZ = bhh[1024 + c0 + p_c];
  const float bN = bhh[2048 + c0 + p_c];
  const int m_t = p_b >> 4;
  const int rrow = p_b & 15;
  float hprev = 0.f;
  const float* xgf = (const float*)xg_;
  const unsigned short* xgh = (const unsigned short*)xg_;
  unsigned int* cnt = bar + bg * 32;

  for (int t = 0; t < 256; ++t) {
    // prefetch xg early (used only in gate phase)
    size_t xi = ((size_t)(t * 128 + b0 + p_b)) * 3072 + c0 + p_c;
    float xr, xz, xn;
    if (XG_F32) { xr = xgf[xi]; xz = xgf[xi + 1024]; xn = xgf[xi + 2048]; }
    else { xr = bf2f(xgh[xi]); xz = bf2f(xgh[xi + 1024]); xn = bf2f(xgh[xi + 2048]); }

    const unsigned short* hH = hbc + (size_t)(t & 1) * 262144;
    const unsigned short* hL = hH + 131072;
    f32x4 acc[3][2] = {};
    const size_t arow0 = (size_t)(b0 + r16) * 1024;
    #pragma unroll
    for (int kc = 0; kc < 4; ++kc) {
      int k = wv * 128 + kc * 32 + r4 * 8;
      s16x8 ah0 = *(const s16x8*)(hH + arow0 + k);
      s16x8 ah1 = *(const s16x8*)(hH + arow0 + 16384 + k);
      s16x8 al0 = *(const s16x8*)(hL + arow0 + k);
      s16x8 al1 = *(const s16x8*)(hL + arow0 + 16384 + k);
      #pragma unroll
      for (int n = 0; n < 3; ++n) {
        acc[n][0] = __builtin_amdgcn_mfma_f32_16x16x32_bf16(al0, bw[n][kc], acc[n][0], 0, 0, 0);
        acc[n][0] = __builtin_amdgcn_mfma_f32_16x16x32_bf16(ah0, bw[n][kc], acc[n][0], 0, 0, 0);
        acc[n][1] = __builtin_amdgcn_mfma_f32_16x16x32_bf16(al1, bw[n][kc], acc[n][1], 0, 0, 0);
        acc[n][1] = __builtin_amdgcn_mfma_f32_16x16x32_bf16(ah1, bw[n][kc], acc[n][1], 0, 0, 0);
      }
    }
    #pragma unroll
    for (int n = 0; n < 3; ++n)
      #pragma unroll
      for (int m = 0; m < 2; ++m)
        #pragma unroll
        for (int r = 0; r < 4; ++r)
          part[wv][n][m][r4 * 4 + r][r16] = acc[n][m][r];
    __syncthreads();

    float sr = bR, sz = bZ, sn = bN;
    #pragma unroll
    for (int q = 0; q < 8; ++q) {
      sr += part[q][0][m_t][rrow][p_c];
      sz += part[q][1][m_t][rrow][p_c];
      sn += part[q][2][m_t][rrow][p_c];
    }
    float rg = 1.f / (1.f + expf(-(xr + sr)));
    float zg = 1.f / (1.f + expf(-(xz + sz)));
    float ng = tanhf(xn + rg * sn);
    float h = (1.f - zg) * ng + zg * hprev;
    hprev = h;
    out[(size_t)t * 131072 + (size_t)(b0 + p_b) * 1024 + c0 + p_c] = h;

    unsigned short hi = f2bf(h);
    unsigned short lo = f2bf(h - bf2f(hi));
    unsigned short* wH = hbc + (size_t)((t + 1) & 1) * 262144;
    size_t widx = (size_t)(b0 + p_b) * 1024 + c0 + p_c;
    wH[widx] = hi;
    wH[131072 + widx] = lo;

    // inter-block barrier (64 blocks sharing this batch-group)
    __threadfence();
    __syncthreads();
    if (tid == 0) {
      __hip_atomic_fetch_add(cnt, 1u, __ATOMIC_RELEASE, __HIP_MEMORY_SCOPE_AGENT);
      unsigned tgt = 64u * (unsigned)(t + 1);
      while (__hip_atomic_load(cnt, __ATOMIC_ACQUIRE, __HIP_MEMORY_SCOPE_AGENT) < tgt) {
        __builtin_amdgcn_s_sleep(2);
      }
    }
    __syncthreads();
  }
}

extern "C" void kernel_launch(void* const* d_in, const int* in_sizes, int n_in,
                              void* d_out, int out_size, void* d_ws, size_t ws_size,
                              hipStream_t stream) {
  const float* x   = (const float*)d_in[0];
  const float* wih = (const float*)d_in[1];
  const float* whh = (const float*)d_in[2];
  const float* bih = (const float*)d_in[3];
  const float* bhh = (const float*)d_in[4];
  float* out = (float*)d_out;

  const size_t xg_f32_bytes = (size_t)32768 * 3072 * 4;   // 384 MiB
  const size_t tail = 4 * 262144 + 1024;                  // h ping-pong (1 MiB) + barriers
  const bool use_f32 = (ws_size >= xg_f32_bytes + tail);
  const size_t xg_bytes = use_f32 ? xg_f32_bytes : xg_f32_bytes / 2;

  char* ws = (char*)d_ws;
  void* xg = ws;
  unsigned short* hbc = (unsigned short*)(ws + xg_bytes);
  unsigned int* bar = (unsigned int*)(ws + xg_bytes + 4 * 262144);

  hipMemsetAsync(hbc, 0, tail, stream);
  if (use_f32) {
    xg_gemm<true><<<dim3(24, 256), 256, 0, stream>>>(x, wih, bih, xg);
    gru_scan<true><<<dim3(64, 4), 512, 0, stream>>>(xg, whh, bhh, out, hbc, bar);
  } else {
    xg_gemm<false><<<dim3(24, 256), 256, 0, stream>>>(x, wih, bih, xg);
    gru_scan<false><<<dim3(64, 4), 512, 0, stream>>>(xg, whh, bhh, out, hbc, bar);
  }
}

// Round 2
// 2231.493 us; speedup vs baseline: 8.3258x; 8.3258x over previous
//
#include <hip/hip_runtime.h>
#include <hip/hip_bf16.h>
#include <cstdint>
#include <cstddef>

// GRU: T=256, B=128, I=H=1024, 3H=3072. fp32 in/out.
// Phase 1: xg[t,b,g] = sum_i x[t,b,i]*w_ih[g,i] + b_ih[g]   (bf16 MFMA GEMM)
// Phase 2: persistent 256-block scan; W_hh slice in VGPRs; hi/lo bf16 h split.
// R1 fix: all cross-block traffic bypasses L1/L2 (sc0 sc1); barrier uses
// RELAXED agent atomics only -> no buffer_inv/buffer_wbl2 per step.

typedef __attribute__((ext_vector_type(4))) float f32x4;
typedef __attribute__((ext_vector_type(8))) short s16x8;
typedef __attribute__((ext_vector_type(4))) unsigned short u16x4;

static __device__ __forceinline__ unsigned short f2bf(float f) {
  union { float f; unsigned u; } v; v.f = f;
  unsigned u = v.u;
  u += 0x7FFFu + ((u >> 16) & 1u);   // round-to-nearest-even
  return (unsigned short)(u >> 16);
}
static __device__ __forceinline__ float bf2f(unsigned short h) {
  union { unsigned u; float f; } v; v.u = ((unsigned)h) << 16;
  return v.f;
}

// 16B load that reads through to the device coherence point (no L1/L2 staleness).
static __device__ __forceinline__ s16x8 ld_bypass(const unsigned short* p) {
  s16x8 r;
  asm volatile("global_load_dwordx4 %0, %1, off sc0 sc1"
               : "=v"(r) : "v"(p) : "memory");
  return r;
}
// 2B write-through store to the coherence point.
static __device__ __forceinline__ void st_bypass(unsigned short* p, unsigned short v) {
  unsigned vv = v;
  asm volatile("global_store_short %0, %1, off sc0 sc1"
               :: "v"(p), "v"(vv) : "memory");
}

// ---------------- Phase 1: xg GEMM ----------------
template<bool XG_F32>
__global__ __launch_bounds__(256)
void xg_gemm(const float* __restrict__ X,     // [32768,1024]
             const float* __restrict__ W,     // [3072,1024]  (B^T layout)
             const float* __restrict__ bias,  // [3072]
             void* __restrict__ xg)           // [32768,3072] f32 or bf16
{
  __shared__ unsigned short Al[128][72];
  __shared__ unsigned short Bl[128][72];
  const int tid = threadIdx.x;
  const int lane = tid & 63;
  const int wv = tid >> 6;
  const int wm = (wv & 1) * 64;
  const int wn = (wv >> 1) * 64;
  const int m0 = blockIdx.y * 128;
  const int n0 = blockIdx.x * 128;
  const int r16 = lane & 15, r4 = lane >> 4;
  f32x4 acc[4][4] = {};

  for (int k0 = 0; k0 < 1024; k0 += 64) {
    __syncthreads();
    #pragma unroll
    for (int i = 0; i < 8; ++i) {
      int f4 = i * 256 + tid;
      int row = f4 >> 4;
      int c4 = f4 & 15;
      f32x4 a = *(const f32x4*)(X + (size_t)(m0 + row) * 1024 + k0 + c4 * 4);
      f32x4 b = *(const f32x4*)(W + (size_t)(n0 + row) * 1024 + k0 + c4 * 4);
      u16x4 ua = { f2bf(a.x), f2bf(a.y), f2bf(a.z), f2bf(a.w) };
      u16x4 ub = { f2bf(b.x), f2bf(b.y), f2bf(b.z), f2bf(b.w) };
      *(u16x4*)&Al[row][c4 * 4] = ua;
      *(u16x4*)&Bl[row][c4 * 4] = ub;
    }
    __syncthreads();
    #pragma unroll
    for (int kk = 0; kk < 64; kk += 32) {
      s16x8 af[4], bf[4];
      #pragma unroll
      for (int mi = 0; mi < 4; ++mi)
        af[mi] = *(const s16x8*)&Al[wm + mi * 16 + r16][kk + r4 * 8];
      #pragma unroll
      for (int ni = 0; ni < 4; ++ni)
        bf[ni] = *(const s16x8*)&Bl[wn + ni * 16 + r16][kk + r4 * 8];
      #pragma unroll
      for (int mi = 0; mi < 4; ++mi)
        #pragma unroll
        for (int ni = 0; ni < 4; ++ni)
          acc[mi][ni] = __builtin_amdgcn_mfma_f32_16x16x32_bf16(af[mi], bf[ni], acc[mi][ni], 0, 0, 0);
    }
  }
  #pragma unroll
  for (int ni = 0; ni < 4; ++ni) {
    float bv = bias[n0 + wn + ni * 16 + r16];
    #pragma unroll
    for (int mi = 0; mi < 4; ++mi) {
      #pragma unroll
      for (int r = 0; r < 4; ++r) {
        int m = m0 + wm + mi * 16 + r4 * 4 + r;
        int n = n0 + wn + ni * 16 + r16;
        float v = acc[mi][ni][r] + bv;
        if (XG_F32) ((float*)xg)[(size_t)m * 3072 + n] = v;
        else        ((unsigned short*)xg)[(size_t)m * 3072 + n] = f2bf(v);
      }
    }
  }
}

// ---------------- Phase 2: persistent GRU scan ----------------
template<bool XG_F32>
__global__ __launch_bounds__(512)
void gru_scan(const void* __restrict__ xg_,
              const float* __restrict__ Whh,   // [3072,1024]
              const float* __restrict__ bhh,   // [3072]
              float* __restrict__ out,         // [256,128,1024]
              unsigned short* __restrict__ hbc,// 2 parities x (hi,lo) x [128][1024]
              unsigned int* __restrict__ bar)  // 4 counters, 128B apart
{
  __shared__ float part[8][3][2][16][20];   // [ks][gate][mtile][row][col+pad]
  const int tid = threadIdx.x;
  const int lane = tid & 63;
  const int wv = tid >> 6;        // K-eighth
  const int cg = blockIdx.x;      // 0..63
  const int bg = blockIdx.y;      // 0..3
  const int c0 = cg * 16;
  const int b0 = bg * 32;
  const int r16 = lane & 15, r4 = lane >> 4;

  // Load this wave's W_hh fragments into registers (once).
  s16x8 bw[3][4];
  #pragma unroll
  for (int n = 0; n < 3; ++n) {
    const float* wrow = Whh + (size_t)(n * 1024 + c0 + r16) * 1024;
    #pragma unroll
    for (int kc = 0; kc < 4; ++kc) {
      int k = wv * 128 + kc * 32 + r4 * 8;
      f32x4 v0 = *(const f32x4*)(wrow + k);
      f32x4 v1 = *(const f32x4*)(wrow + k + 4);
      s16x8 f;
      f[0] = (short)f2bf(v0.x); f[1] = (short)f2bf(v0.y);
      f[2] = (short)f2bf(v0.z); f[3] = (short)f2bf(v0.w);
      f[4] = (short)f2bf(v1.x); f[5] = (short)f2bf(v1.y);
      f[6] = (short)f2bf(v1.z); f[7] = (short)f2bf(v1.w);
      bw[n][kc] = f;
    }
  }

  const int p_b = tid >> 4;       // 0..31 (batch within group)
  const int p_c = tid & 15;       // h-col within group
  const float bR = bhh[c0 + p_c];
  const float bZ = bhh[1024 + c0 + p_c];
  const float bN = bhh[2048 + c0 + p_c];
  const int m_t = p_b >> 4;
  const int rrow = p_b & 15;
  float hprev = 0.f;
  const float* xgf = (const float*)xg_;
  const unsigned short* xgh = (const unsigned short*)xg_;
  unsigned int* cnt = bar + bg * 32;
  const size_t arow0 = (size_t)(b0 + r16) * 1024;

  // prefetch xg for t=0
  float xr, xz, xn;
  {
    size_t xi = ((size_t)(b0 + p_b)) * 3072 + c0 + p_c;
    if (XG_F32) { xr = xgf[xi]; xz = xgf[xi + 1024]; xn = xgf[xi + 2048]; }
    else { xr = bf2f(xgh[xi]); xz = bf2f(xgh[xi + 1024]); xn = bf2f(xgh[xi + 2048]); }
  }

  for (int t = 0; t < 256; ++t) {
    const unsigned short* hH = hbc + (size_t)(t & 1) * 262144;
    const unsigned short* hL = hH + 131072;

    // Issue all 16 cache-bypassing h loads, then one explicit drain.
    s16x8 ah0[4], ah1[4], al0[4], al1[4];
    #pragma unroll
    for (int kc = 0; kc < 4; ++kc) {
      int k = wv * 128 + kc * 32 + r4 * 8;
      ah0[kc] = ld_bypass(hH + arow0 + k);
      ah1[kc] = ld_bypass(hH + arow0 + 16384 + k);
      al0[kc] = ld_bypass(hL + arow0 + k);
      al1[kc] = ld_bypass(hL + arow0 + 16384 + k);
    }
    asm volatile("s_waitcnt vmcnt(0)" ::: "memory");
    __builtin_amdgcn_sched_barrier(0);

    f32x4 acc[3][2] = {};
    #pragma unroll
    for (int kc = 0; kc < 4; ++kc) {
      #pragma unroll
      for (int n = 0; n < 3; ++n) {
        acc[n][0] = __builtin_amdgcn_mfma_f32_16x16x32_bf16(al0[kc], bw[n][kc], acc[n][0], 0, 0, 0);
        acc[n][0] = __builtin_amdgcn_mfma_f32_16x16x32_bf16(ah0[kc], bw[n][kc], acc[n][0], 0, 0, 0);
        acc[n][1] = __builtin_amdgcn_mfma_f32_16x16x32_bf16(al1[kc], bw[n][kc], acc[n][1], 0, 0, 0);
        acc[n][1] = __builtin_amdgcn_mfma_f32_16x16x32_bf16(ah1[kc], bw[n][kc], acc[n][1], 0, 0, 0);
      }
    }
    #pragma unroll
    for (int n = 0; n < 3; ++n)
      #pragma unroll
      for (int m = 0; m < 2; ++m)
        #pragma unroll
        for (int r = 0; r < 4; ++r)
          part[wv][n][m][r4 * 4 + r][r16] = acc[n][m][r];
    __syncthreads();

    float sr = bR, sz = bZ, sn = bN;
    #pragma unroll
    for (int q = 0; q < 8; ++q) {
      sr += part[q][0][m_t][rrow][p_c];
      sz += part[q][1][m_t][rrow][p_c];
      sn += part[q][2][m_t][rrow][p_c];
    }
    float rg = 1.f / (1.f + expf(-(xr + sr)));
    float zg = 1.f / (1.f + expf(-(xz + sz)));
    float ng = tanhf(xn + rg * sn);
    float h = (1.f - zg) * ng + zg * hprev;
    hprev = h;
    out[(size_t)t * 131072 + (size_t)(b0 + p_b) * 1024 + c0 + p_c] = h;

    // write-through h broadcast (hi/lo bf16)
    unsigned short hi = f2bf(h);
    unsigned short lo = f2bf(h - bf2f(hi));
    unsigned short* wH = hbc + (size_t)((t + 1) & 1) * 262144;
    size_t widx = (size_t)(b0 + p_b) * 1024 + c0 + p_c;
    st_bypass(wH + widx, hi);
    st_bypass(wH + 131072 + widx, lo);

    // drain own stores, then workgroup barrier: all waves' h is at the IF
    asm volatile("s_waitcnt vmcnt(0)" ::: "memory");
    __syncthreads();

    // arrival: relaxed agent RMW (no wbl2, no inv)
    if (tid == 0)
      __hip_atomic_fetch_add(cnt, 1u, __ATOMIC_RELAXED, __HIP_MEMORY_SCOPE_AGENT);

    // prefetch next xg while the barrier settles
    if (t < 255) {
      size_t xi = ((size_t)((t + 1) * 128 + b0 + p_b)) * 3072 + c0 + p_c;
      if (XG_F32) { xr = xgf[xi]; xz = xgf[xi + 1024]; xn = xgf[xi + 2048]; }
      else { xr = bf2f(xgh[xi]); xz = bf2f(xgh[xi + 1024]); xn = bf2f(xgh[xi + 2048]); }
    }

    // relaxed polls only — no cache maintenance per poll
    if (tid == 0) {
      unsigned tgt = 64u * (unsigned)(t + 1);
      while (__hip_atomic_load(cnt, __ATOMIC_RELAXED, __HIP_MEMORY_SCOPE_AGENT) < tgt)
        __builtin_amdgcn_s_sleep(2);
    }
    __syncthreads();
  }
}

extern "C" void kernel_launch(void* const* d_in, const int* in_sizes, int n_in,
                              void* d_out, int out_size, void* d_ws, size_t ws_size,
                              hipStream_t stream) {
  const float* x   = (const float*)d_in[0];
  const float* wih = (const float*)d_in[1];
  const float* whh = (const float*)d_in[2];
  const float* bih = (const float*)d_in[3];
  const float* bhh = (const float*)d_in[4];
  float* out = (float*)d_out;

  const size_t xg_f32_bytes = (size_t)32768 * 3072 * 4;   // 384 MiB
  const size_t tail = 4 * 262144 + 1024;                  // h ping-pong (1 MiB) + barriers
  const bool use_f32 = (ws_size >= xg_f32_bytes + tail);
  const size_t xg_bytes = use_f32 ? xg_f32_bytes : xg_f32_bytes / 2;

  char* ws = (char*)d_ws;
  void* xg = ws;
  unsigned short* hbc = (unsigned short*)(ws + xg_bytes);
  unsigned int* bar = (unsigned int*)(ws + xg_bytes + 4 * 262144);

  hipMemsetAsync(hbc, 0, tail, stream);
  if (use_f32) {
    xg_gemm<true><<<dim3(24, 256), 256, 0, stream>>>(x, wih, bih, xg);
    gru_scan<true><<<dim3(64, 4), 512, 0, stream>>>(xg, whh, bhh, out, hbc, bar);
  } else {
    xg_gemm<false><<<dim3(24, 256), 256, 0, stream>>>(x, wih, bih, xg);
    gru_scan<false><<<dim3(64, 4), 512, 0, stream>>>(xg, whh, bhh, out, hbc, bar);
  }
}

// Round 3
// 1940.447 us; speedup vs baseline: 9.5746x; 1.1500x over previous
//
#include <hip/hip_runtime.h>
#include <hip/hip_bf16.h>
#include <cstdint>
#include <cstddef>

// GRU: T=256, B=128, I=H=1024, 3H=3072. fp32 in/out.
// Phase 1: xg[t,b,g] = x·W_ih^T + b_ih  (bf16 MFMA GEMM)
// Phase 2: persistent 128-block scan (32 col-groups x 4 batch-groups).
//   h broadcast = single bf16, write-through (sc0 sc1), parity ping-pong.
//   Flag-array barrier (no atomic RMW serialization, no cache maintenance).

typedef __attribute__((ext_vector_type(4))) float f32x4;
typedef __attribute__((ext_vector_type(8))) short s16x8;
typedef __attribute__((ext_vector_type(4))) unsigned short u16x4;

static __device__ __forceinline__ unsigned short f2bf(float f) {
  union { float f; unsigned u; } v; v.f = f;
  unsigned u = v.u;
  u += 0x7FFFu + ((u >> 16) & 1u);   // RNE
  return (unsigned short)(u >> 16);
}
static __device__ __forceinline__ float bf2f(unsigned short h) {
  union { unsigned u; float f; } v; v.u = ((unsigned)h) << 16;
  return v.f;
}

static __device__ __forceinline__ s16x8 ld_bypass(const unsigned short* p) {
  s16x8 r;
  asm volatile("global_load_dwordx4 %0, %1, off sc0 sc1"
               : "=v"(r) : "v"(p) : "memory");
  return r;
}
static __device__ __forceinline__ void st_bypass(unsigned short* p, unsigned short v) {
  unsigned vv = v;
  asm volatile("global_store_short %0, %1, off sc0 sc1"
               :: "v"(p), "v"(vv) : "memory");
}
static __device__ __forceinline__ void st_flag(unsigned int* p, unsigned v) {
  asm volatile("global_store_dword %0, %1, off sc0 sc1"
               :: "v"(p), "v"(v) : "memory");
}
static __device__ __forceinline__ unsigned ld_flag(const unsigned int* p) {
  unsigned r;
  asm volatile("global_load_dword %0, %1, off sc0 sc1\n\ts_waitcnt vmcnt(0)"
               : "=v"(r) : "v"(p) : "memory");
  return r;
}

// ---------------- Phase 1: xg GEMM ----------------
template<bool XG_F32>
__global__ __launch_bounds__(256)
void xg_gemm(const float* __restrict__ X,     // [32768,1024]
             const float* __restrict__ W,     // [3072,1024]  (B^T layout)
             const float* __restrict__ bias,  // [3072]
             void* __restrict__ xg)           // [32768,3072] f32 or bf16
{
  __shared__ unsigned short Al[128][72];
  __shared__ unsigned short Bl[128][72];
  const int tid = threadIdx.x;
  const int lane = tid & 63;
  const int wv = tid >> 6;
  const int wm = (wv & 1) * 64;
  const int wn = (wv >> 1) * 64;
  const int m0 = blockIdx.y * 128;
  const int n0 = blockIdx.x * 128;
  const int r16 = lane & 15, r4 = lane >> 4;
  f32x4 acc[4][4] = {};

  for (int k0 = 0; k0 < 1024; k0 += 64) {
    __syncthreads();
    #pragma unroll
    for (int i = 0; i < 8; ++i) {
      int f4 = i * 256 + tid;
      int row = f4 >> 4;
      int c4 = f4 & 15;
      f32x4 a = *(const f32x4*)(X + (size_t)(m0 + row) * 1024 + k0 + c4 * 4);
      f32x4 b = *(const f32x4*)(W + (size_t)(n0 + row) * 1024 + k0 + c4 * 4);
      u16x4 ua = { f2bf(a.x), f2bf(a.y), f2bf(a.z), f2bf(a.w) };
      u16x4 ub = { f2bf(b.x), f2bf(b.y), f2bf(b.z), f2bf(b.w) };
      *(u16x4*)&Al[row][c4 * 4] = ua;
      *(u16x4*)&Bl[row][c4 * 4] = ub;
    }
    __syncthreads();
    #pragma unroll
    for (int kk = 0; kk < 64; kk += 32) {
      s16x8 af[4], bf[4];
      #pragma unroll
      for (int mi = 0; mi < 4; ++mi)
        af[mi] = *(const s16x8*)&Al[wm + mi * 16 + r16][kk + r4 * 8];
      #pragma unroll
      for (int ni = 0; ni < 4; ++ni)
        bf[ni] = *(const s16x8*)&Bl[wn + ni * 16 + r16][kk + r4 * 8];
      #pragma unroll
      for (int mi = 0; mi < 4; ++mi)
        #pragma unroll
        for (int ni = 0; ni < 4; ++ni)
          acc[mi][ni] = __builtin_amdgcn_mfma_f32_16x16x32_bf16(af[mi], bf[ni], acc[mi][ni], 0, 0, 0);
    }
  }
  #pragma unroll
  for (int ni = 0; ni < 4; ++ni) {
    float bv = bias[n0 + wn + ni * 16 + r16];
    #pragma unroll
    for (int mi = 0; mi < 4; ++mi) {
      #pragma unroll
      for (int r = 0; r < 4; ++r) {
        int m = m0 + wm + mi * 16 + r4 * 4 + r;
        int n = n0 + wn + ni * 16 + r16;
        float v = acc[mi][ni][r] + bv;
        if (XG_F32) ((float*)xg)[(size_t)m * 3072 + n] = v;
        else        ((unsigned short*)xg)[(size_t)m * 3072 + n] = f2bf(v);
      }
    }
  }
}

// ---------------- Phase 2: persistent GRU scan ----------------
// grid (32,4): cg -> 32 h-cols (96 gate rows), bg -> 32 batch rows.
// 8 waves; wave wv owns K-eighth. Two-round LDS partial reduce (52KB).
template<bool XG_F32>
__global__ __launch_bounds__(512)
void gru_scan(const void* __restrict__ xg_,
              const float* __restrict__ Whh,   // [3072,1024]
              const float* __restrict__ bhh,   // [3072]
              float* __restrict__ out,         // [256,128,1024]
              unsigned short* __restrict__ hbc,// 2 parities x [128][1024] bf16
              unsigned int* __restrict__ bar)  // 4 x 32 flags (128B apart)
{
  __shared__ float part[4][3][2][2][16][17];   // [q][gate][ntile][mtile][row][col+1]
  const int tid = threadIdx.x;
  const int lane = tid & 63;
  const int wv = tid >> 6;        // K-eighth
  const int cg = blockIdx.x;      // 0..31
  const int bg = blockIdx.y;      // 0..3
  const int c0 = cg * 32;
  const int b0 = bg * 32;
  const int r16 = lane & 15, r4 = lane >> 4;

  // W_hh fragments in registers: bw[gate][ntile][kc]
  s16x8 bw[3][2][4];
  #pragma unroll
  for (int n = 0; n < 3; ++n) {
    #pragma unroll
    for (int nt = 0; nt < 2; ++nt) {
      const float* wrow = Whh + (size_t)(n * 1024 + c0 + nt * 16 + r16) * 1024;
      #pragma unroll
      for (int kc = 0; kc < 4; ++kc) {
        int k = wv * 128 + kc * 32 + r4 * 8;
        f32x4 v0 = *(const f32x4*)(wrow + k);
        f32x4 v1 = *(const f32x4*)(wrow + k + 4);
        s16x8 f;
        f[0] = (short)f2bf(v0.x); f[1] = (short)f2bf(v0.y);
        f[2] = (short)f2bf(v0.z); f[3] = (short)f2bf(v0.w);
        f[4] = (short)f2bf(v1.x); f[5] = (short)f2bf(v1.y);
        f[6] = (short)f2bf(v1.z); f[7] = (short)f2bf(v1.w);
        bw[n][nt][kc] = f;
      }
    }
  }

  const int p_c = tid & 31;       // col within group
  const int rb = tid >> 5;        // 0..15: owns rows rb and rb+16
  const int nt_g = p_c >> 4, c16 = p_c & 15;
  const float bR = bhh[c0 + p_c];
  const float bZ = bhh[1024 + c0 + p_c];
  const float bN = bhh[2048 + c0 + p_c];
  float hprev0 = 0.f, hprev1 = 0.f;
  const float* xgf = (const float*)xg_;
  const unsigned short* xgh = (const unsigned short*)xg_;
  unsigned int* flags = bar + bg * 32;
  const size_t arow0 = (size_t)(b0 + r16) * 1024;

  float xr0, xz0, xn0, xr1, xz1, xn1;
  {
    size_t xi = ((size_t)(b0 + rb)) * 3072 + c0 + p_c;
    size_t xj = xi + (size_t)16 * 3072;
    if (XG_F32) {
      xr0 = xgf[xi]; xz0 = xgf[xi + 1024]; xn0 = xgf[xi + 2048];
      xr1 = xgf[xj]; xz1 = xgf[xj + 1024]; xn1 = xgf[xj + 2048];
    } else {
      xr0 = bf2f(xgh[xi]); xz0 = bf2f(xgh[xi + 1024]); xn0 = bf2f(xgh[xi + 2048]);
      xr1 = bf2f(xgh[xj]); xz1 = bf2f(xgh[xj + 1024]); xn1 = bf2f(xgh[xj + 2048]);
    }
  }

  for (int t = 0; t < 256; ++t) {
    const unsigned short* hH = hbc + (size_t)(t & 1) * 131072;

    // 8 bypass loads of h fragments (2 m-tiles x 4 kc), one drain.
    s16x8 ah[2][4];
    #pragma unroll
    for (int kc = 0; kc < 4; ++kc) {
      int k = wv * 128 + kc * 32 + r4 * 8;
      ah[0][kc] = ld_bypass(hH + arow0 + k);
      ah[1][kc] = ld_bypass(hH + arow0 + 16384 + k);
    }
    asm volatile("s_waitcnt vmcnt(0)" ::: "memory");
    __builtin_amdgcn_sched_barrier(0);

    f32x4 acc[3][2][2] = {};
    #pragma unroll
    for (int kc = 0; kc < 4; ++kc)
      #pragma unroll
      for (int n = 0; n < 3; ++n)
        #pragma unroll
        for (int nt = 0; nt < 2; ++nt) {
          acc[n][nt][0] = __builtin_amdgcn_mfma_f32_16x16x32_bf16(ah[0][kc], bw[n][nt][kc], acc[n][nt][0], 0, 0, 0);
          acc[n][nt][1] = __builtin_amdgcn_mfma_f32_16x16x32_bf16(ah[1][kc], bw[n][nt][kc], acc[n][nt][1], 0, 0, 0);
        }

    // two-round partial reduce: waves 0-3 write, waves 4-7 accumulate
    if (wv < 4) {
      #pragma unroll
      for (int n = 0; n < 3; ++n)
        #pragma unroll
        for (int nt = 0; nt < 2; ++nt)
          #pragma unroll
          for (int m = 0; m < 2; ++m)
            #pragma unroll
            for (int r = 0; r < 4; ++r)
              part[wv][n][nt][m][r4 * 4 + r][r16] = acc[n][nt][m][r];
    }
    __syncthreads();
    if (wv >= 4) {
      #pragma unroll
      for (int n = 0; n < 3; ++n)
        #pragma unroll
        for (int nt = 0; nt < 2; ++nt)
          #pragma unroll
          for (int m = 0; m < 2; ++m)
            #pragma unroll
            for (int r = 0; r < 4; ++r)
              part[wv - 4][n][nt][m][r4 * 4 + r][r16] += acc[n][nt][m][r];
    }
    __syncthreads();

    // gate phase: each thread owns (rb, p_c) and (rb+16, p_c)
    float sr0 = bR, sz0 = bZ, sn0 = bN;
    float sr1 = bR, sz1 = bZ, sn1 = bN;
    #pragma unroll
    for (int q = 0; q < 4; ++q) {
      sr0 += part[q][0][nt_g][0][rb][c16];
      sz0 += part[q][1][nt_g][0][rb][c16];
      sn0 += part[q][2][nt_g][0][rb][c16];
      sr1 += part[q][0][nt_g][1][rb][c16];
      sz1 += part[q][1][nt_g][1][rb][c16];
      sn1 += part[q][2][nt_g][1][rb][c16];
    }
    float rg0 = 1.f / (1.f + expf(-(xr0 + sr0)));
    float zg0 = 1.f / (1.f + expf(-(xz0 + sz0)));
    float ng0 = tanhf(xn0 + rg0 * sn0);
    float h0 = (1.f - zg0) * ng0 + zg0 * hprev0;
    float rg1 = 1.f / (1.f + expf(-(xr1 + sr1)));
    float zg1 = 1.f / (1.f + expf(-(xz1 + sz1)));
    float ng1 = tanhf(xn1 + rg1 * sn1);
    float h1 = (1.f - zg1) * ng1 + zg1 * hprev1;
    hprev0 = h0; hprev1 = h1;

    size_t oidx = (size_t)t * 131072 + (size_t)(b0 + rb) * 1024 + c0 + p_c;
    out[oidx] = h0;
    out[oidx + 16384] = h1;

    unsigned short* wH = hbc + (size_t)((t + 1) & 1) * 131072;
    size_t widx = (size_t)(b0 + rb) * 1024 + c0 + p_c;
    st_bypass(wH + widx, f2bf(h0));
    st_bypass(wH + widx + 16384, f2bf(h1));

    // drain all this wave's VMEM (h + out stores), then block-wide sync
    asm volatile("s_waitcnt vmcnt(0)" ::: "memory");
    __syncthreads();

    // arrival flag (one store), xg prefetch, then 1-wave poll
    if (tid == 0) st_flag(flags + cg, (unsigned)(t + 1));
    if (t < 255) {
      size_t xi = ((size_t)((t + 1) * 128 + b0 + rb)) * 3072 + c0 + p_c;
      size_t xj = xi + (size_t)16 * 3072;
      if (XG_F32) {
        xr0 = xgf[xi]; xz0 = xgf[xi + 1024]; xn0 = xgf[xi + 2048];
        xr1 = xgf[xj]; xz1 = xgf[xj + 1024]; xn1 = xgf[xj + 2048];
      } else {
        xr0 = bf2f(xgh[xi]); xz0 = bf2f(xgh[xi + 1024]); xn0 = bf2f(xgh[xi + 2048]);
        xr1 = bf2f(xgh[xj]); xz1 = bf2f(xgh[xj + 1024]); xn1 = bf2f(xgh[xj + 2048]);
      }
    }
    if (wv == 0) {
      unsigned tgt = (unsigned)(t + 1);
      for (;;) {
        unsigned v = ld_flag(flags + (lane & 31));
        if (!__ballot(v < tgt)) break;
        __builtin_amdgcn_s_sleep(1);
      }
    }
    __syncthreads();
  }
}

extern "C" void kernel_launch(void* const* d_in, const int* in_sizes, int n_in,
                              void* d_out, int out_size, void* d_ws, size_t ws_size,
                              hipStream_t stream) {
  const float* x   = (const float*)d_in[0];
  const float* wih = (const float*)d_in[1];
  const float* whh = (const float*)d_in[2];
  const float* bih = (const float*)d_in[3];
  const float* bhh = (const float*)d_in[4];
  float* out = (float*)d_out;

  const size_t xg_f32_bytes = (size_t)32768 * 3072 * 4;   // 384 MiB
  const size_t tail = 2 * 262144 + 512;                   // h ping-pong (512KB) + flags
  const bool use_f32 = (ws_size >= xg_f32_bytes + tail);
  const size_t xg_bytes = use_f32 ? xg_f32_bytes : xg_f32_bytes / 2;

  char* ws = (char*)d_ws;
  void* xg = ws;
  unsigned short* hbc = (unsigned short*)(ws + xg_bytes);
  unsigned int* bar = (unsigned int*)(ws + xg_bytes + 2 * 262144);

  hipMemsetAsync(hbc, 0, tail, stream);
  if (use_f32) {
    xg_gemm<true><<<dim3(24, 256), 256, 0, stream>>>(x, wih, bih, xg);
    gru_scan<true><<<dim3(32, 4), 512, 0, stream>>>(xg, whh, bhh, out, hbc, bar);
  } else {
    xg_gemm<false><<<dim3(24, 256), 256, 0, stream>>>(x, wih, bih, xg);
    gru_scan<false><<<dim3(32, 4), 512, 0, stream>>>(xg, whh, bhh, out, hbc, bar);
  }
}